// Round 4
// baseline (989.456 us; speedup 1.0000x reference)
//
#include <hip/hip_runtime.h>
#include <stdint.h>

// out[M,N] = x[M,K] @ W'[N,K]^T + bias[N], W' = W + SCALE*(loraB @ loraA)
// M = 16384 (B*S), N = 4096, K = 4096. SCALE = 16/16 = 1.0.
#define M_DIM 16384
#define N_DIM 4096
#define K_DIM 4096
#define LORA_SCALE 1.0f

#define BM 256
#define BN 256
#define BK 64
#define NT (K_DIM / BK)  // 64 K-tiles

typedef _Float16 half8 __attribute__((ext_vector_type(8)));
typedef float f32x4 __attribute__((ext_vector_type(4)));

// ---------------------------------------------------------------------------
// Kernel 1 (fused prep), all-streaming:
//  blocks [0, 8192):      W'[n,k] = W[n,k] + sum_r lB[n,r]*lA[r,k] -> f16
//                         (8 k-elems/thread, lB row scalar via readfirstlane,
//                          lA from L2; BW-bound, no LDS, no syncs)
//  blocks [8192, 40960):  x fp32 -> f16, 8 elems/thread.
// ---------------------------------------------------------------------------
__global__ __launch_bounds__(256) void prep_kernel(const float* __restrict__ x,
                                                   _Float16* __restrict__ xb,
                                                   const float* __restrict__ W,
                                                   const float* __restrict__ lA,
                                                   const float* __restrict__ lB,
                                                   _Float16* __restrict__ wp) {
    const int t = threadIdx.x;
    const int WBLK = (N_DIM * K_DIM) / (256 * 8);  // 8192

    if (blockIdx.x < WBLK) {
        const size_t base = ((size_t)blockIdx.x * 256 + t) * 8;
        const int n = (int)(base >> 12);           // / K_DIM
        const int k = (int)(base & (K_DIM - 1));
        // Wave covers 512 consecutive elems, never straddles a row -> n uniform.
        const int ns = __builtin_amdgcn_readfirstlane(n);
        float Brow[16];
#pragma unroll
        for (int r = 0; r < 16; ++r) Brow[r] = lB[(size_t)ns * 16 + r];

        f32x4 w0 = *(const f32x4*)(W + base);
        f32x4 w1 = *(const f32x4*)(W + base + 4);
        f32x4 d0 = {0.f, 0.f, 0.f, 0.f}, d1 = {0.f, 0.f, 0.f, 0.f};
#pragma unroll
        for (int r = 0; r < 16; ++r) {
            const float* ar = lA + (size_t)r * K_DIM + k;
            f32x4 a0 = *(const f32x4*)ar;
            f32x4 a1 = *(const f32x4*)(ar + 4);
            d0 += Brow[r] * a0;
            d1 += Brow[r] * a1;
        }
        w0 += LORA_SCALE * d0;
        w1 += LORA_SCALE * d1;
        half8 h;
        h[0] = (_Float16)w0[0]; h[1] = (_Float16)w0[1];
        h[2] = (_Float16)w0[2]; h[3] = (_Float16)w0[3];
        h[4] = (_Float16)w1[0]; h[5] = (_Float16)w1[1];
        h[6] = (_Float16)w1[2]; h[7] = (_Float16)w1[3];
        *(half8*)(wp + base) = h;
        return;
    }

    const size_t base = ((size_t)(blockIdx.x - WBLK) * 256 + t) * 8;
    f32x4 a = *(const f32x4*)(x + base);
    f32x4 b = *(const f32x4*)(x + base + 4);
    half8 h;
    h[0] = (_Float16)a[0]; h[1] = (_Float16)a[1];
    h[2] = (_Float16)a[2]; h[3] = (_Float16)a[3];
    h[4] = (_Float16)b[0]; h[5] = (_Float16)b[1];
    h[6] = (_Float16)b[2]; h[7] = (_Float16)b[3];
    *(half8*)(xb + base) = h;
}

// ---------------------------------------------------------------------------
// Kernel 2: 256x256 GEMM, BK=64, 8 waves (2m x 4n), 4 phases/K-tile decomposed
// by (k-half, m-half): reads {8,4,8,4} ds_read_b128/phase, 16 MFMA/phase,
// B-frags of a k-half held in regs across 2 phases. Half-tile ring (8 slots),
// staging 3 half-tiles ahead, vmcnt(6) per tile. C=sum_k A[m,k]B[n,k]+bias.
// ---------------------------------------------------------------------------
__device__ __forceinline__ void load_lds16(const void* g, void* l) {
    __builtin_amdgcn_global_load_lds(
        (const __attribute__((address_space(1))) unsigned int*)(uintptr_t)g,
        (__attribute__((address_space(3))) unsigned int*)(uintptr_t)l,
        16, 0, 0);
}

__global__ __launch_bounds__(512, 2) void gemm256_kernel(const _Float16* __restrict__ A,
                                                         const _Float16* __restrict__ B,
                                                         const float* __restrict__ bias,
                                                         float* __restrict__ C) {
    // Slots [dbuf][khalf][256 rows][32 f16]; read swizzle k-slot' = quad ^
    // ((row>>1)&3); staging pre-swizzles the global source col (rule 21).
    __shared__ _Float16 As[2][2][256 * 32];  // 4 x 16 KiB
    __shared__ _Float16 Bs[2][2][256 * 32];  // 4 x 16 KiB -> 128 KiB

    const int tid  = threadIdx.x;
    const int lane = tid & 63;
    const int wave = tid >> 6;
    const int wm   = wave >> 2;   // 0..1 : m-half (128 rows)
    const int wn   = wave & 3;    // 0..3 : n-quarter (64 cols)
    const int quad = lane >> 4;
    const int r16  = lane & 15;
    const int swz  = (quad ^ ((r16 >> 1) & 3)) << 3;

    // XCD-bijective remap: 1024 wgs -> 128 contiguous tiles per XCD.
    const int bid = blockIdx.x;
    const int id  = (bid & 7) * 128 + (bid >> 3);
    const int m0  = (id >> 4) * BM;
    const int n0  = (id & 15) * BN;

    // Staging addressing (per thread, 2 chunks per half-tile).
    const int  srow = tid >> 2;
    const int  scol = (((tid & 3) ^ ((tid >> 3) & 3)) << 3);
    const _Float16* gA = A + (size_t)(m0 + srow) * K_DIM + scol;
    const _Float16* gB = B + (size_t)(n0 + srow) * K_DIM + scol;
    const int ldst0 = tid * 8;
    const int ldst1 = (tid + 512) * 8;

    const int arow = (wm * 128 + r16) * 32 + swz;
    const int brow = (wn * 64 + r16) * 32 + swz;

    f32x4 acc[8][4] = {};
    half8 a[4], b[4];

#define ISSUE_A(DB, KH, T) do { \
        const _Float16* g_ = gA + (size_t)((T) * 64 + (KH) * 32); \
        load_lds16(g_, &As[DB][KH][ldst0]); \
        load_lds16(g_ + (size_t)128 * K_DIM, &As[DB][KH][ldst1]); \
    } while (0)
#define ISSUE_B(DB, KH, T) do { \
        const _Float16* g_ = gB + (size_t)((T) * 64 + (KH) * 32); \
        load_lds16(g_, &Bs[DB][KH][ldst0]); \
        load_lds16(g_ + (size_t)128 * K_DIM, &Bs[DB][KH][ldst1]); \
    } while (0)

#define MID() do { \
        asm volatile("" ::: "memory"); __builtin_amdgcn_sched_barrier(0); \
        __builtin_amdgcn_s_barrier(); \
        asm volatile("s_waitcnt lgkmcnt(0)" ::: "memory"); \
        __builtin_amdgcn_sched_barrier(0); \
        __builtin_amdgcn_s_setprio(1); \
    } while (0)
#define ENDP() do { \
        __builtin_amdgcn_s_setprio(0); \
        asm volatile("" ::: "memory"); __builtin_amdgcn_sched_barrier(0); \
        __builtin_amdgcn_s_barrier(); \
    } while (0)

#define MFMA16(MLO) \
        _Pragma("unroll") \
        for (int i_ = 0; i_ < 4; ++i_) \
            _Pragma("unroll") \
            for (int j_ = 0; j_ < 4; ++j_) \
                acc[(MLO) + i_][j_] = __builtin_amdgcn_mfma_f32_16x16x32_f16( \
                    a[i_], b[j_], acc[(MLO) + i_][j_], 0, 0, 0);

// Phase reading B(khalf)+A(m-half 0): 8 reads. Phase reading A(m-half 1): 4.
#define PH_BA(DB, KH, ISS) do { \
        _Pragma("unroll") \
        for (int j_ = 0; j_ < 4; ++j_) b[j_] = *(const half8*)&Bs[DB][KH][brow + j_ * 512]; \
        _Pragma("unroll") \
        for (int i_ = 0; i_ < 4; ++i_) a[i_] = *(const half8*)&As[DB][KH][arow + i_ * 512]; \
        ISS; MID(); MFMA16(0) ENDP(); \
    } while (0)
#define PH_A2(DB, KH, ISS) do { \
        _Pragma("unroll") \
        for (int i_ = 0; i_ < 4; ++i_) a[i_] = *(const half8*)&As[DB][KH][arow + (i_ + 4) * 512]; \
        ISS; MID(); MFMA16(4) ENDP(); \
    } while (0)
#define PH_A2L(DB, KH, ISS) do { \
        _Pragma("unroll") \
        for (int i_ = 0; i_ < 4; ++i_) a[i_] = *(const half8*)&As[DB][KH][arow + (i_ + 4) * 512]; \
        ISS; MID(); MFMA16(4) \
    } while (0)

// Stream order per tile: [B-k0, A-k0, B-k1, A-k1]. Issues at tile t:
// p0 -> A[1-DB][1]@t+1 (dead since t-1 p3), p1 -> B[DB][0]@t+2 (dead p0),
// p2 -> A[DB][0]@t+2 (dead p1), p3 -> B[DB][1]@t+2 (dead p2).
#define TILE(DB, T1, T2) do { \
        PH_BA(DB, 0, ISSUE_A(1 - (DB), 1, T1)); \
        PH_A2(DB, 0, ISSUE_B(DB, 0, T2)); \
        PH_BA(DB, 1, ISSUE_A(DB, 0, T2)); \
        PH_A2L(DB, 1, ISSUE_B(DB, 1, T2)); \
    } while (0)
#define ENDT6() do { \
        __builtin_amdgcn_s_setprio(0); \
        asm volatile("" ::: "memory"); __builtin_amdgcn_sched_barrier(0); \
        asm volatile("s_waitcnt vmcnt(6)" ::: "memory"); \
        __builtin_amdgcn_s_barrier(); \
    } while (0)

    // Prologue: streams 0..6 (tile 0 complete + 3 half-tiles of tile 1).
    ISSUE_B(0, 0, 0); ISSUE_A(0, 0, 0); ISSUE_B(0, 1, 0); ISSUE_A(0, 1, 0);
    ISSUE_B(1, 0, 1); ISSUE_A(1, 0, 1); ISSUE_B(1, 1, 1);
    asm volatile("s_waitcnt vmcnt(6)" ::: "memory");  // tile 0 landed
    __builtin_amdgcn_s_barrier();

#pragma unroll 1
    for (int ip = 0; ip < 31; ++ip) {  // tiles 0..61
        const int t1 = 2 * ip + 1, t2 = 2 * ip + 2, t3 = 2 * ip + 3;
        TILE(0, t1, t2);
        ENDT6();
        TILE(1, t2, t3);
        ENDT6();
    }
    // Tile 62: only stream 255 (tile 63 A-k1) remains; then full drain.
    PH_BA(0, 0, ISSUE_A(1, 1, 63));
    PH_A2(0, 0, (void)0);
    PH_BA(0, 1, (void)0);
    PH_A2L(0, 1, (void)0);
    __builtin_amdgcn_s_setprio(0);
    asm volatile("" ::: "memory"); __builtin_amdgcn_sched_barrier(0);
    asm volatile("s_waitcnt vmcnt(0)" ::: "memory");  // tile 63 fully landed
    __builtin_amdgcn_s_barrier();
    // Tile 63: no issues.
    PH_BA(1, 0, (void)0);
    PH_A2(1, 0, (void)0);
    PH_BA(1, 1, (void)0);
    PH_A2L(1, 1, (void)0);
    __builtin_amdgcn_s_setprio(0);

#undef TILE
#undef ENDT6
#undef PH_BA
#undef PH_A2
#undef PH_A2L
#undef MFMA16
#undef MID
#undef ENDP
#undef ISSUE_A
#undef ISSUE_B

    // Epilogue: C/D layout col = lane&15 (n), row = quad*4 + reg (m).
#pragma unroll
    for (int j = 0; j < 4; ++j) {
        const int n = n0 + wn * 64 + j * 16 + r16;
        const float bv = bias[n];
#pragma unroll
        for (int i = 0; i < 8; ++i) {
            const int mbase = m0 + wm * 128 + i * 16 + quad * 4;
#pragma unroll
            for (int r = 0; r < 4; ++r) {
                C[(size_t)(mbase + r) * N_DIM + n] = acc[i][j][r] + bv;
            }
        }
    }
}

// ---------------------------------------------------------------------------
extern "C" void kernel_launch(void* const* d_in, const int* in_sizes, int n_in,
                              void* d_out, int out_size, void* d_ws, size_t ws_size,
                              hipStream_t stream) {
    const float* x      = (const float*)d_in[0];  // [4,4096,4096] fp32 -> [M,K]
    const float* weight = (const float*)d_in[1];  // [N,K] fp32
    const float* bias   = (const float*)d_in[2];  // [N] fp32
    const float* lora_A = (const float*)d_in[3];  // [16,K] fp32
    const float* lora_B = (const float*)d_in[4];  // [N,16] fp32
    float* out = (float*)d_out;

    _Float16* xb = (_Float16*)d_ws;                                       // 128 MiB
    _Float16* wp = (_Float16*)((char*)d_ws + (size_t)M_DIM * K_DIM * 2);  // +32 MiB

    // 1) fused streaming prep: W' (8192 blocks) + x->f16 (32768 blocks)
    const int wblk = (N_DIM * K_DIM) / (256 * 8);
    const int xblk = (int)((M_DIM * (size_t)K_DIM) / (256 * 8));
    prep_kernel<<<dim3(wblk + xblk), dim3(256), 0, stream>>>(x, xb, weight, lora_A, lora_B, wp);
    // 2) GEMM + bias (256x256 tiles, 1024 wgs)
    gemm256_kernel<<<dim3((M_DIM / BM) * (N_DIM / BN)), dim3(512), 0, stream>>>(xb, wp, bias, out);
}